// Round 6
// baseline (1032.416 us; speedup 1.0000x reference)
//
#include <hip/hip_runtime.h>

#define TOTAL_BITS 8
#define MSE_BLOCKS 2048
#define QUANT_BLOCKS 2048

// ws layout (floats):
//   [8] = step, [9] = scale, [10] = qmin, [11] = qmax   (written by fpq_select)
//   [16 + 8*b + f] = block b's partial sum of squared error for candidate f
//
// Scaled-domain identity used throughout (exact for power-of-2 scales):
//   clamp(w, qmin_f, qmax_f) * 2^f == clamp(w * 2^f, -2^(b-1), 2^(b-1)-1)
// so the clamp bounds are the f-independent constants -128 / 127, and the
// whole quantize-error is: e = w - 2^-f * rint(clamp(w*2^f, -128, 127)).

// native vector type for __builtin_nontemporal_store (HIP float4 is a class)
typedef float f32x4 __attribute__((ext_vector_type(4)));

__global__ __launch_bounds__(256) void fpq_mse(const float* __restrict__ x,
                                               float* __restrict__ ws,
                                               long long n) {
    constexpr float QLO = -(float)(1 << (TOTAL_BITS - 1));       // -128
    constexpr float QHI = (float)(1 << (TOTAL_BITS - 1)) - 1.0f; //  127

    float acc[TOTAL_BITS];
#pragma unroll
    for (int f = 0; f < TOTAL_BITS; ++f) acc[f] = 0.0f;

    const long long nch = n >> 3; // 8-float (32 B) chunks
    const float4* __restrict__ xv = (const float4*)x;
    const long long tid = (long long)blockIdx.x * blockDim.x + threadIdx.x;
    const long long stride = (long long)gridDim.x * blockDim.x;

    // forward sweep: leaves the TAIL of x resident in the 256 MB LLC for fpq_quant
    for (long long i = tid; i < nch; i += stride) {
        const float4 a = xv[2 * i];
        const float4 b = xv[2 * i + 1];
        const float vals[8] = {a.x, a.y, a.z, a.w, b.x, b.y, b.z, b.w};
#pragma unroll
        for (int j = 0; j < 8; ++j) {
            const float w = vals[j];
#pragma unroll
            for (int f = 0; f < TOTAL_BITS; ++f) {
                const float scale = (float)(1 << f);        // 2^f (SGPR-hoisted)
                const float step  = 1.0f / (float)(1 << f); // 2^-f
                float s = w * scale;                        // exact
                float c = fminf(fmaxf(s, QLO), QHI);        // v_med3-able, const bounds
                float r = rintf(c);                         // round-half-even == jnp.round
                float e = fmaf(-r, step, w);                // w - r*step, r*step exact
                acc[f] = fmaf(e, e, acc[f]);
            }
        }
    }
    // scalar tail (defensive; n % 8 == 0 for this problem)
    for (long long i = (nch << 3) + tid; i < n; i += stride) {
        const float w = x[i];
#pragma unroll
        for (int f = 0; f < TOTAL_BITS; ++f) {
            const float scale = (float)(1 << f);
            const float step  = 1.0f / (float)(1 << f);
            float s = w * scale;
            float c = fminf(fmaxf(s, QLO), QHI);
            float r = rintf(c);
            float e = fmaf(-r, step, w);
            acc[f] = fmaf(e, e, acc[f]);
        }
    }

    // wave-64 shuffle reduce -> LDS (shared-mem atomics, 32 per block) -> one
    // non-atomic global write of 8 partials per block. No global atomics.
    __shared__ float sm[TOTAL_BITS];
    if (threadIdx.x < TOTAL_BITS) sm[threadIdx.x] = 0.0f;
    __syncthreads();
#pragma unroll
    for (int f = 0; f < TOTAL_BITS; ++f) {
        float v = acc[f];
#pragma unroll
        for (int off = 32; off > 0; off >>= 1) v += __shfl_down(v, off, 64);
        if ((threadIdx.x & 63) == 0) atomicAdd(&sm[f], v);
    }
    __syncthreads();
    if (threadIdx.x < TOTAL_BITS)
        ws[16 + 8 * (long long)blockIdx.x + threadIdx.x] = sm[threadIdx.x];
}

__global__ void fpq_select(float* __restrict__ ws, int nblocks) {
    // one block, 256 threads: sum 8*nblocks partials, argmin, write constants
    __shared__ float sm[TOTAL_BITS];
    if (threadIdx.x < TOTAL_BITS) sm[threadIdx.x] = 0.0f;
    __syncthreads();
    const int f = threadIdx.x & 7;
    float acc = 0.0f;
    for (int b = threadIdx.x >> 3; b < nblocks; b += (int)blockDim.x >> 3)
        acc += ws[16 + 8 * (long long)b + f];
    atomicAdd(&sm[f], acc);
    __syncthreads();
    if (threadIdx.x == 0) {
        int best = 0;
        float bm = sm[0];
        for (int g = 1; g < TOTAL_BITS; ++g) {
            if (sm[g] < bm) { bm = sm[g]; best = g; }  // strict < == first-min (jnp.argmin)
        }
        float scale = (float)(1 << best);
        float step  = 1.0f / scale;
        float base  = (float)(1 << (TOTAL_BITS - 1 - best));
        ws[8]  = step;
        ws[9]  = scale;
        ws[10] = -base;
        ws[11] = base - step;
    }
}

__global__ __launch_bounds__(256) void fpq_quant(const float* __restrict__ x,
                                                 float* __restrict__ out,
                                                 const float* __restrict__ ws,
                                                 long long n) {
    constexpr float QLO = -(float)(1 << (TOTAL_BITS - 1));       // -128
    constexpr float QHI = (float)(1 << (TOTAL_BITS - 1)) - 1.0f; //  127
    const float step  = ws[8];
    const float scale = ws[9];

    const long long nch = n >> 3; // 8-float (32 B) chunks
    const float4* __restrict__ xv = (const float4*)x;
    f32x4* __restrict__ ov = (f32x4*)out;
    const long long tid = (long long)blockIdx.x * blockDim.x + threadIdx.x;
    const long long stride = (long long)gridDim.x * blockDim.x;

    // REVERSE sweep: read the tail of x first while it is still LLC-resident
    // from fpq_mse's forward sweep. All QUANT_BLOCKS are co-resident (tiny
    // kernel), so the grid walks backward in contiguous bands.
    for (long long k = tid; k < nch; k += stride) {
        const long long i = nch - 1 - k;
        const float4 a = xv[2 * i];
        const float4 b = xv[2 * i + 1];
        f32x4 oa, ob;
        oa.x = rintf(fminf(fmaxf(a.x * scale, QLO), QHI)) * step;
        oa.y = rintf(fminf(fmaxf(a.y * scale, QLO), QHI)) * step;
        oa.z = rintf(fminf(fmaxf(a.z * scale, QLO), QHI)) * step;
        oa.w = rintf(fminf(fmaxf(a.w * scale, QLO), QHI)) * step;
        ob.x = rintf(fminf(fmaxf(b.x * scale, QLO), QHI)) * step;
        ob.y = rintf(fminf(fmaxf(b.y * scale, QLO), QHI)) * step;
        ob.z = rintf(fminf(fmaxf(b.z * scale, QLO), QHI)) * step;
        ob.w = rintf(fminf(fmaxf(b.w * scale, QLO), QHI)) * step;
        // non-temporal: out is write-once, never re-read; keep LLC for x
        __builtin_nontemporal_store(oa, &ov[2 * i]);
        __builtin_nontemporal_store(ob, &ov[2 * i + 1]);
    }
    // scalar tail (defensive; n % 8 == 0 for this problem)
    for (long long i = (nch << 3) + tid; i < n; i += stride) {
        out[i] = rintf(fminf(fmaxf(x[i] * scale, QLO), QHI)) * step;
    }
}

extern "C" void kernel_launch(void* const* d_in, const int* in_sizes, int n_in,
                              void* d_out, int out_size, void* d_ws, size_t ws_size,
                              hipStream_t stream) {
    const float* x = (const float*)d_in[0];
    float* out = (float*)d_out;
    float* ws = (float*)d_ws;
    const long long n = (long long)in_sizes[0];

    fpq_mse<<<MSE_BLOCKS, 256, 0, stream>>>(x, ws, n);
    fpq_select<<<1, 256, 0, stream>>>(ws, MSE_BLOCKS);
    fpq_quant<<<QUANT_BLOCKS, 256, 0, stream>>>(x, out, ws, n);
}

// Round 7
// 868.375 us; speedup vs baseline: 1.1889x; 1.1889x over previous
//
#include <hip/hip_runtime.h>

#define TOTAL_BITS 8
#define GUESS_F 5       // speculative best_f; verified by fpq_select, fallback in fpq_quant
#define MSE_BLOCKS 2048
#define QUANT_BLOCKS 2048

// ws layout (floats):
//   [8] = step, [9] = scale, [10] = qmin, [11] = qmax   (written by fpq_select)
//   [12] = 1.0f if argmin(mse) == GUESS_F else 0.0f     (speculation verdict)
//   [16 + 8*b + f] = block b's partial sum of squared error for candidate f
//
// Scaled-domain identity used throughout (exact for power-of-2 scales):
//   clamp(w, qmin_f, qmax_f) * 2^f == clamp(w * 2^f, -2^(b-1), 2^(b-1)-1)
// so the clamp bounds are the f-independent constants -128 / 127, and the
// whole quantize-error is: e = w - 2^-f * rint(clamp(w*2^f, -128, 127)).
//
// SPECULATION: fpq_mse also writes out = quantize(x, GUESS_F) during its pass
// (turns the pure-read pass into a copy-like pass, ~same duration class).
// fpq_select verifies the guess; on hit fpq_quant is a no-op, eliminating the
// second 537 MB read + 537 MB write of x/out. On miss fpq_quant overwrites out
// with the correct quantization — exact for ANY input, just slower.

__global__ __launch_bounds__(256) void fpq_mse(const float* __restrict__ x,
                                               float* __restrict__ out,
                                               float* __restrict__ ws,
                                               long long n) {
    constexpr float QLO = -(float)(1 << (TOTAL_BITS - 1));       // -128
    constexpr float QHI = (float)(1 << (TOTAL_BITS - 1)) - 1.0f; //  127

    float acc[TOTAL_BITS];
#pragma unroll
    for (int f = 0; f < TOTAL_BITS; ++f) acc[f] = 0.0f;

    const long long nch = n >> 3; // 8-float (32 B) chunks
    const float4* __restrict__ xv = (const float4*)x;
    float4* __restrict__ ov = (float4*)out;
    const long long tid = (long long)blockIdx.x * blockDim.x + threadIdx.x;
    const long long stride = (long long)gridDim.x * blockDim.x;

    for (long long i = tid; i < nch; i += stride) {
        const float4 a = xv[2 * i];
        const float4 b = xv[2 * i + 1];
        const float vals[8] = {a.x, a.y, a.z, a.w, b.x, b.y, b.z, b.w};
        float q[8];
#pragma unroll
        for (int j = 0; j < 8; ++j) {
            const float w = vals[j];
#pragma unroll
            for (int f = 0; f < TOTAL_BITS; ++f) {
                const float scale = (float)(1 << f);        // 2^f
                const float step  = 1.0f / (float)(1 << f); // 2^-f
                float s = w * scale;                        // exact
                float c = fminf(fmaxf(s, QLO), QHI);        // v_med3, const bounds
                float r = rintf(c);                         // round-half-even == jnp.round
                float e = fmaf(-r, step, w);                // w - r*step (exact r*step)
                acc[f] = fmaf(e, e, acc[f]);
                if (f == GUESS_F) q[j] = r * step;          // speculative output (CSE'd)
            }
        }
        float4 oa, ob;
        oa.x = q[0]; oa.y = q[1]; oa.z = q[2]; oa.w = q[3];
        ob.x = q[4]; ob.y = q[5]; ob.z = q[6]; ob.w = q[7];
        ov[2 * i] = oa;
        ov[2 * i + 1] = ob;
    }
    // scalar tail (defensive; n % 8 == 0 for this problem)
    for (long long i = (nch << 3) + tid; i < n; i += stride) {
        const float w = x[i];
        float qv = 0.0f;
#pragma unroll
        for (int f = 0; f < TOTAL_BITS; ++f) {
            const float scale = (float)(1 << f);
            const float step  = 1.0f / (float)(1 << f);
            float s = w * scale;
            float c = fminf(fmaxf(s, QLO), QHI);
            float r = rintf(c);
            float e = fmaf(-r, step, w);
            acc[f] = fmaf(e, e, acc[f]);
            if (f == GUESS_F) qv = r * step;
        }
        out[i] = qv;
    }

    // wave-64 shuffle reduce -> LDS (shared-mem atomics, 32 per block) -> one
    // non-atomic global write of 8 partials per block. No global atomics.
    __shared__ float sm[TOTAL_BITS];
    if (threadIdx.x < TOTAL_BITS) sm[threadIdx.x] = 0.0f;
    __syncthreads();
#pragma unroll
    for (int f = 0; f < TOTAL_BITS; ++f) {
        float v = acc[f];
#pragma unroll
        for (int off = 32; off > 0; off >>= 1) v += __shfl_down(v, off, 64);
        if ((threadIdx.x & 63) == 0) atomicAdd(&sm[f], v);
    }
    __syncthreads();
    if (threadIdx.x < TOTAL_BITS)
        ws[16 + 8 * (long long)blockIdx.x + threadIdx.x] = sm[threadIdx.x];
}

__global__ void fpq_select(float* __restrict__ ws, int nblocks) {
    // one block, 256 threads: sum 8*nblocks partials, argmin, write constants
    __shared__ float sm[TOTAL_BITS];
    if (threadIdx.x < TOTAL_BITS) sm[threadIdx.x] = 0.0f;
    __syncthreads();
    const int f = threadIdx.x & 7;
    float acc = 0.0f;
    for (int b = threadIdx.x >> 3; b < nblocks; b += (int)blockDim.x >> 3)
        acc += ws[16 + 8 * (long long)b + f];
    atomicAdd(&sm[f], acc);
    __syncthreads();
    if (threadIdx.x == 0) {
        int best = 0;
        float bm = sm[0];
        for (int g = 1; g < TOTAL_BITS; ++g) {
            if (sm[g] < bm) { bm = sm[g]; best = g; }  // strict < == first-min (jnp.argmin)
        }
        float scale = (float)(1 << best);
        float step  = 1.0f / scale;
        float base  = (float)(1 << (TOTAL_BITS - 1 - best));
        ws[8]  = step;
        ws[9]  = scale;
        ws[10] = -base;
        ws[11] = base - step;
        ws[12] = (best == GUESS_F) ? 1.0f : 0.0f;  // speculation verdict
    }
}

__global__ __launch_bounds__(256) void fpq_quant(const float* __restrict__ x,
                                                 float* __restrict__ out,
                                                 const float* __restrict__ ws,
                                                 long long n) {
    constexpr float QLO = -(float)(1 << (TOTAL_BITS - 1));       // -128
    constexpr float QHI = (float)(1 << (TOTAL_BITS - 1)) - 1.0f; //  127

    if (ws[12] != 0.0f) return;  // speculation hit: out already holds exact result

    const float step  = ws[8];
    const float scale = ws[9];

    const long long nch = n >> 3; // 8-float (32 B) chunks
    const float4* __restrict__ xv = (const float4*)x;
    float4* __restrict__ ov = (float4*)out;
    const long long tid = (long long)blockIdx.x * blockDim.x + threadIdx.x;
    const long long stride = (long long)gridDim.x * blockDim.x;

    for (long long i = tid; i < nch; i += stride) {
        const float4 a = xv[2 * i];
        const float4 b = xv[2 * i + 1];
        float4 oa, ob;
        oa.x = rintf(fminf(fmaxf(a.x * scale, QLO), QHI)) * step;
        oa.y = rintf(fminf(fmaxf(a.y * scale, QLO), QHI)) * step;
        oa.z = rintf(fminf(fmaxf(a.z * scale, QLO), QHI)) * step;
        oa.w = rintf(fminf(fmaxf(a.w * scale, QLO), QHI)) * step;
        ob.x = rintf(fminf(fmaxf(b.x * scale, QLO), QHI)) * step;
        ob.y = rintf(fminf(fmaxf(b.y * scale, QLO), QHI)) * step;
        ob.z = rintf(fminf(fmaxf(b.z * scale, QLO), QHI)) * step;
        ob.w = rintf(fminf(fmaxf(b.w * scale, QLO), QHI)) * step;
        ov[2 * i] = oa;
        ov[2 * i + 1] = ob;
    }
    // scalar tail (defensive; n % 8 == 0 for this problem)
    for (long long i = (nch << 3) + tid; i < n; i += stride) {
        out[i] = rintf(fminf(fmaxf(x[i] * scale, QLO), QHI)) * step;
    }
}

extern "C" void kernel_launch(void* const* d_in, const int* in_sizes, int n_in,
                              void* d_out, int out_size, void* d_ws, size_t ws_size,
                              hipStream_t stream) {
    const float* x = (const float*)d_in[0];
    float* out = (float*)d_out;
    float* ws = (float*)d_ws;
    const long long n = (long long)in_sizes[0];

    fpq_mse<<<MSE_BLOCKS, 256, 0, stream>>>(x, out, ws, n);
    fpq_select<<<1, 256, 0, stream>>>(ws, MSE_BLOCKS);
    fpq_quant<<<QUANT_BLOCKS, 256, 0, stream>>>(x, out, ws, n);
}